// Round 6
// baseline (230.642 us; speedup 1.0000x reference)
//
#include <hip/hip_runtime.h>
#include <math.h>

// Problem constants: B=4, GL=4, GF=128, N=1024, CS=32, CN=16, NA=16, S=512
//
// Flat views (fp32, per b):
//  X   : [512 k][1024 n]
//  U   : [128 c][1024 n] ; P2 view: [1024 m][128 q], q=k*32+i, scale sc[l], l=m>>8
//  S   : [1024 m][512 ju]  (UNsquashed)   ju=j*32+u
//  MS  : [1024 m][32 u]    squash scale per (m,u)
//  UH  : [8192]            u_hat for aspect routing, e = i*512 + j*32 + u
//  WGR : [128 q][32 u][16 j] reordered Wg (built once)
//  SSp : [b][l][16 nt] partial sum-of-squares (no zero-init needed: pure stores)
//  Bgp : [b][16 mc][8 jt][64] partial b-logits (tbu stores iter0, adds after)
//  Gp  : [b][16 mt][512] partial G (smatmul #3 stores; uhat sums)

static constexpr int OFF_U   = 0;          // 524288
static constexpr int OFF_S   = 524288;     // 2097152 -> end 2621440
static constexpr int OFF_SSP = 2621440;    // 256
static constexpr int OFF_BGP = 2621696;    // 32768 -> end 2654464
static constexpr int OFF_GP  = 2654464;    // 32768 -> end 2687232
static constexpr int OFF_VA  = 2687232;    // 2048  -> end 2689280
static constexpr int OFF_MS  = 2689280;    // 131072 -> end 2820352
static constexpr int OFF_UH  = 2820352;    // 32768 -> end 2853120
static constexpr int OFF_WGR = 2853120;    // 65536 -> end 2918656 (< 2922512 proven bound)

// ---------------------------------------------------------------------------
// K1 "primaryF": full-K primary-capsule GEMM, fused bias + U write + SS partial.
// grid (2 ct, 16 nt, 5 z): z<4 = b (full K=512 per block, 4 staged chunks);
// z==4: 32 blocks do the one-time Wg reorder.
// U accumulation order: k ascending 0..511 per output (was 4 pairwise partials).
__global__ void k_primaryF(const float* __restrict__ X, const float* __restrict__ Wp,
                           const float* __restrict__ bp,
                           float* __restrict__ U, float* __restrict__ SSp,
                           const float* __restrict__ Wg, float* __restrict__ Wgr)
{
    __shared__ float Wt[128 * 68];
    __shared__ float red[256];
    const int t = threadIdx.x;
    if (blockIdx.z == 4) {
        // Wgr[q*512 + u*16 + j] = Wg[((i*16+j)*32+u)*4 + kk], q = kk*32+i
        const int blk = blockIdx.x * 16 + blockIdx.y;       // 0..31
#pragma unroll
        for (int r = 0; r < 8; ++r) {
            const int e = blk * 2048 + r * 256 + t;         // 0..65535
            const int q = e >> 9, rem = e & 511;
            const int u = rem >> 4, j = rem & 15;
            const int i = q & 31, kk = q >> 5;
            Wgr[e] = Wg[((i * 16 + j) * 32 + u) * 4 + kk];
        }
        return;
    }
    const int ct = blockIdx.x, nt = blockIdx.y, b = blockIdx.z;
    const int tn = t & 15, tc = t >> 4;
    const int c0 = ct * 64, n0 = nt * 64;
    float acc[4][4] = {};
    for (int ks = 0; ks < 4; ++ks) {
        if (ks) __syncthreads();       // protect Wt reuse
#pragma unroll
        for (int i = 0; i < 8; ++i) {
            const int idx = t + i * 256;
            const int c = idx >> 5, k4 = idx & 31;
            const float4 wv = *(const float4*)&Wp[(size_t)(c0 + c) * 512 + ks * 128 + k4 * 4];
            Wt[(k4 * 4 + 0) * 68 + c] = wv.x;
            Wt[(k4 * 4 + 1) * 68 + c] = wv.y;
            Wt[(k4 * 4 + 2) * 68 + c] = wv.z;
            Wt[(k4 * 4 + 3) * 68 + c] = wv.w;
        }
        __syncthreads();
        const float* Xp = X + (size_t)b * 524288 + (size_t)(ks * 128) * 1024 + n0 + tn * 4;
#pragma unroll 4
        for (int k = 0; k < 128; ++k) {
            const float4 xv = *(const float4*)(Xp + (size_t)k * 1024);
            const float4 wv = *(const float4*)&Wt[k * 68 + tc * 4];
            const float w[4] = {wv.x, wv.y, wv.z, wv.w};
            const float x[4] = {xv.x, xv.y, xv.z, xv.w};
#pragma unroll
            for (int ci = 0; ci < 4; ++ci)
#pragma unroll
                for (int ni = 0; ni < 4; ++ni)
                    acc[ci][ni] = fmaf(w[ci], x[ni], acc[ci][ni]);
        }
    }
    // bias + write U + per-thread ssq
    float ssq = 0.f;
#pragma unroll
    for (int ci = 0; ci < 4; ++ci) {
        const int c = c0 + tc * 4 + ci;
        const float bv = bp[c];
        float4 o = make_float4(acc[ci][0] + bv, acc[ci][1] + bv,
                               acc[ci][2] + bv, acc[ci][3] + bv);
        ssq = fmaf(o.x, o.x, ssq); ssq = fmaf(o.y, o.y, ssq);
        ssq = fmaf(o.z, o.z, ssq); ssq = fmaf(o.w, o.w, ssq);
        *(float4*)&U[(size_t)b * 131072 + (size_t)c * 1024 + n0 + tn * 4] = o;
    }
    // two-half tree reduce (threads <128: l_local 0; >=128: l_local 1)
    red[t] = ssq;
    __syncthreads();
    for (int s = 64; s > 0; s >>= 1) {
        if ((t & 127) < s) red[t] += red[t + s];
        __syncthreads();
    }
    if ((t & 127) == 0)
        SSp[(b * 4 + ct * 2 + (t >> 7)) * 16 + nt] = red[t];
}

// ---------------------------------------------------------------------------
// K4 "smatmulM2": S = (P2*sc) @ (cls o Wg), u-sliced; MS in-block (iters 0,1)
// or Gp partial store (iter 2). cls from Bgp partial sums (bg0: exact 1/16).
// grid (16 mt, 4 us, 4 b), 256 thr, thread tile 4m x 8j.  [structure proven r5]
__global__ __launch_bounds__(256) void k_smatmulM2(
    const float* __restrict__ U, const float* __restrict__ SSp,
    const float* __restrict__ Bgp, const float* __restrict__ Wgr,
    float* __restrict__ S, float* __restrict__ MS, float* __restrict__ Gp,
    const int bg0)
{
    __shared__ __align__(16) float Pt[64 * 68];    // [qL][m]
    __shared__ __align__(16) float Ct[64 * 160];   // [qL][cpad]
    __shared__ float cls[512];
    __shared__ float bgs[512];
    __shared__ float gacc[128];
    const int mt = blockIdx.x, us = blockIdx.y, b = blockIdx.z;
    const int t = threadIdx.x;
    const int tm = t >> 4;
    const int uu = t & 7, jh = (t >> 3) & 1;
    const int m0 = mt * 64;

    if (bg0) {
        cls[t] = 0.0625f;            // softmax(0) == 1/16 exactly
        cls[t + 256] = 0.0625f;
    } else {
#pragma unroll
        for (int h = 0; h < 2; ++h) {
            const int p = t + h * 256;               // (i,j): i=p>>4, j=p&15
            const int i = p >> 4, j = p & 15;
            float s = 0.f;
#pragma unroll 4
            for (int mc = 0; mc < 16; ++mc)
                s += Bgp[((b * 16 + mc) * 8 + (j >> 1)) * 64 + i * 2 + (j & 1)];
            bgs[p] = s * (1.f / 1024.f);
        }
        __syncthreads();
        if (t < 32) {
            float vals[16];
            float mx = -1e30f;
            for (int j = 0; j < 16; ++j) { vals[j] = bgs[t * 16 + j]; mx = fmaxf(mx, vals[j]); }
            float sum = 0.f;
            for (int j = 0; j < 16; ++j) { vals[j] = expf(vals[j] - mx); sum += vals[j]; }
            const float inv = 1.f / sum;
            for (int j = 0; j < 16; ++j) cls[t * 16 + j] = vals[j] * inv;
        }
    }
    if (Gp != nullptr && t < 128) gacc[t] = 0.f;
    // squash scale: uniform 16-float sum of SS partials (scalar-load friendly)
    float ssum = 0.f;
#pragma unroll
    for (int i = 0; i < 16; ++i) ssum += SSp[(b * 4 + (mt >> 2)) * 16 + i];
    const float sc = sqrtf(ssum) / (1.f + ssum);
    float acc[4][8] = {};
    const float* Ub = U + (size_t)b * 131072 + (size_t)m0 * 128;
    __syncthreads();

    for (int kc = 0; kc < 2; ++kc) {
#pragma unroll
        for (int it = 0; it < 4; ++it) {
            const int x = t + it * 256;           // 0..1023
            const int m = x & 63, q4 = x >> 6;    // q4 0..15
            const float4 v = *(const float4*)&Ub[(size_t)m * 128 + kc * 64 + q4 * 4];
            Pt[(q4 * 4 + 0) * 68 + m] = v.x * sc;
            Pt[(q4 * 4 + 1) * 68 + m] = v.y * sc;
            Pt[(q4 * 4 + 2) * 68 + m] = v.z * sc;
            Pt[(q4 * 4 + 3) * 68 + m] = v.w * sc;
        }
#pragma unroll
        for (int it = 0; it < 8; ++it) {
            const int x = t + it * 256;           // 0..2047
            const int c4 = (x & 31) * 4, qL = x >> 5;
            const int q = kc * 64 + qL;
            const int i = q & 31;
            const int j0 = c4 & 15;
            const float4 w = *(const float4*)&Wgr[(size_t)q * 512 + us * 128 + c4];
            const int cp = qL * 160 + c4 + ((c4 >> 4) << 2);
            Ct[cp + 0] = cls[i * 16 + j0 + 0] * w.x;
            Ct[cp + 1] = cls[i * 16 + j0 + 1] * w.y;
            Ct[cp + 2] = cls[i * 16 + j0 + 2] * w.z;
            Ct[cp + 3] = cls[i * 16 + j0 + 3] * w.w;
        }
        __syncthreads();
        const int cbase = uu * 20 + jh * 8;       // cpad of c = uu*16 + jh*8
#pragma unroll 4
        for (int qL = 0; qL < 64; ++qL) {
            const float4 p4 = *(const float4*)&Pt[qL * 68 + tm * 4];
            const float4 ca = *(const float4*)&Ct[qL * 160 + cbase];
            const float4 cb = *(const float4*)&Ct[qL * 160 + cbase + 4];
            const float pm[4] = {p4.x, p4.y, p4.z, p4.w};
            const float cj[8] = {ca.x, ca.y, ca.z, ca.w, cb.x, cb.y, cb.z, cb.w};
#pragma unroll
            for (int mm = 0; mm < 4; ++mm)
#pragma unroll
                for (int jj = 0; jj < 8; ++jj)
                    acc[mm][jj] = fmaf(pm[mm], cj[jj], acc[mm][jj]);
        }
        __syncthreads();
    }

    // store S: ju = (jh*8+jj)*32 + us*8 + uu
#pragma unroll
    for (int mm = 0; mm < 4; ++mm) {
        float* Sp = S + (size_t)b * 524288 + (size_t)(m0 + tm * 4 + mm) * 512 + us * 8 + uu;
#pragma unroll
        for (int jj = 0; jj < 8; ++jj)
            Sp[(jh * 8 + jj) * 32] = acc[mm][jj];
    }

    if (Gp == nullptr) {
        // MS[m][u] from full-j sum of squares (jh pair via shfl)
#pragma unroll
        for (int mm = 0; mm < 4; ++mm) {
            float msq = 0.f;
#pragma unroll
            for (int jj = 0; jj < 8; ++jj) msq = fmaf(acc[mm][jj], acc[mm][jj], msq);
            msq += __shfl_xor(msq, 8);
            if (jh == 0)
                MS[b * 32768 + (m0 + tm * 4 + mm) * 32 + us * 8 + uu] =
                    sqrtf(msq) / (1.f + msq);
        }
    } else {
        // last iter: Gp[b][mt][ju] = (1/1024) sum_{m in tile} S*msc  (pure store)
        float part[8];
#pragma unroll
        for (int jj = 0; jj < 8; ++jj) part[jj] = 0.f;
#pragma unroll
        for (int mm = 0; mm < 4; ++mm) {
            float msq = 0.f;
#pragma unroll
            for (int jj = 0; jj < 8; ++jj) msq = fmaf(acc[mm][jj], acc[mm][jj], msq);
            msq += __shfl_xor(msq, 8);
            const float msc = sqrtf(msq) / (1.f + msq);
#pragma unroll
            for (int jj = 0; jj < 8; ++jj) part[jj] = fmaf(acc[mm][jj], msc, part[jj]);
        }
#pragma unroll
        for (int jj = 0; jj < 8; ++jj)
            atomicAdd(&gacc[(jh * 8 + jj) * 8 + uu], part[jj]);
        __syncthreads();
        if (t < 128) {
            const int j = t >> 3, u2 = t & 7;
            Gp[(size_t)(b * 16 + mt) * 512 + j * 32 + us * 8 + u2] =
                gacc[t] * (1.f / 1024.f);
        }
    }
}

// ---------------------------------------------------------------------------
// K6 "tbu2": b-update into Bgp partial slots (first: store, else: add).
// grid (8 jt, 16 mc, 4 b), 256 thr.  [core proven]
__global__ void k_tbu2(const float* __restrict__ U, const float* __restrict__ SSp,
                       const float* __restrict__ S, const float* __restrict__ MS,
                       const float* __restrict__ Wg, float* __restrict__ Bgp,
                       const int first)
{
    __shared__ float Ps[64 * 132];   // [m][q], pad 132
    __shared__ float Vs[64 * 68];    // [m][jv], pad 68
    __shared__ float bup[64];        // [i][j_loc]
    const int jt = blockIdx.x, mc = blockIdx.y, b = blockIdx.z;
    const int t = threadIdx.x;
    const int tq = t & 31, tjv = t >> 5;
    const int m0 = mc * 64;
    if (t < 64) bup[t] = 0.f;
    float ssum = 0.f;
#pragma unroll
    for (int i = 0; i < 16; ++i) ssum += SSp[(b * 4 + (mc >> 2)) * 16 + i];
    const float sc = sqrtf(ssum) / (1.f + ssum);
#pragma unroll
    for (int i = 0; i < 8; ++i) {
        const int f4 = t + i * 256;
        const int r = f4 >> 5, q4 = f4 & 31;
        float4 v = *(const float4*)&U[(size_t)b * 131072 + (size_t)(m0 + r) * 128 + q4 * 4];
        v.x *= sc; v.y *= sc; v.z *= sc; v.w *= sc;
        *(float4*)&Ps[r * 132 + q4 * 4] = v;
    }
#pragma unroll
    for (int i = 0; i < 4; ++i) {
        const int f4 = t + i * 256;
        const int r = f4 >> 4, c4 = f4 & 15;
        const int m = m0 + r;
        float4 v = *(const float4*)&S[(size_t)b * 524288 + (size_t)m * 512 + jt * 64 + c4 * 4];
        const int ub = (c4 * 4) & 31;
        const float* msp = MS + b * 32768 + m * 32;
        v.x *= msp[ub + 0]; v.y *= msp[ub + 1]; v.z *= msp[ub + 2]; v.w *= msp[ub + 3];
        *(float4*)&Vs[r * 68 + c4 * 4] = v;
    }
    __syncthreads();
    float acc[4][8] = {};
#pragma unroll 2
    for (int m = 0; m < 64; ++m) {
        const float4 p4 = *(const float4*)&Ps[m * 132 + tq * 4];
        const float4 va = *(const float4*)&Vs[m * 68 + tjv * 8];
        const float4 vb = *(const float4*)&Vs[m * 68 + tjv * 8 + 4];
        const float pv[4] = {p4.x, p4.y, p4.z, p4.w};
        const float vv[8] = {va.x, va.y, va.z, va.w, vb.x, vb.y, vb.z, vb.w};
#pragma unroll
        for (int qi = 0; qi < 4; ++qi)
#pragma unroll
            for (int ji = 0; ji < 8; ++ji)
                acc[qi][ji] = fmaf(pv[qi], vv[ji], acc[qi][ji]);
    }
    const int k = tq >> 3;
    const int j_loc = tjv >> 2;
    const int j = jt * 2 + j_loc;
    const int u0 = (tjv & 3) * 8;
#pragma unroll
    for (int qi = 0; qi < 4; ++qi) {
        const int i = (tq & 7) * 4 + qi;
        const float* wp = Wg + ((i * 16 + j) * 32) * 4 + k;
        float s = 0.f;
#pragma unroll
        for (int ji = 0; ji < 8; ++ji)
            s = fmaf(wp[(u0 + ji) * 4], acc[qi][ji], s);
        s += __shfl_xor(s, 8);
        s += __shfl_xor(s, 16);
        s += __shfl_xor(s, 32);
        if ((t & 56) == 0) atomicAdd(&bup[i * 2 + j_loc], s);
    }
    __syncthreads();
    if (t < 64) {
        float* slot = &Bgp[((b * 16 + mc) * 8 + jt) * 64 + t];
        if (first) *slot = bup[t];
        else       *slot += bup[t];
    }
}

// ---------------------------------------------------------------------------
// K8a "uhat2": attention + aspect u_hat; G from Gp partials. grid (8, 4 b).
__global__ void k_uhat2(const float* __restrict__ Gp, const float* __restrict__ Wa,
                        const float* __restrict__ Ws, float* __restrict__ UH)
{
    const int b = blockIdx.y;
    const int t = threadIdx.x;
    __shared__ float g[512], cond[512], score[16], red[16];
    float g0 = 0.f, g1 = 0.f;
#pragma unroll 4
    for (int mt = 0; mt < 16; ++mt) {
        const float* gp = Gp + (size_t)(b * 16 + mt) * 512;
        g0 += gp[t];
        g1 += gp[t + 256];
    }
    g[t] = g0;
    g[t + 256] = g1;
    __syncthreads();
    if (t < 16) {
        float s = 0.f;
        for (int u = 0; u < 32; ++u) s = fmaf(g[t * 32 + u], Wa[u], s);
        red[t] = s;
    }
    __syncthreads();
    if (t == 0) {
        float mx = -1e30f;
        for (int j = 0; j < 16; ++j) mx = fmaxf(mx, red[j]);
        float sum = 0.f;
        for (int j = 0; j < 16; ++j) { score[j] = expf(red[j] - mx); sum += score[j]; }
        const float inv = 1.f / sum;
        for (int j = 0; j < 16; ++j) score[j] *= inv;
    }
    __syncthreads();
    cond[t] = g[t] * score[t >> 5];
    cond[t + 256] = g[t + 256] * score[(t + 256) >> 5];
    __syncthreads();
    const int e0 = blockIdx.x * 1024 + t * 4;
    const int i = e0 >> 9;
    const float* cp = cond + i * 32;
    const float* wp = Ws + (size_t)e0 * 32;
    float res[4];
#pragma unroll
    for (int jj = 0; jj < 4; ++jj) {
        float s = 0.f;
#pragma unroll
        for (int k8 = 0; k8 < 8; ++k8) {
            const float4 w = *(const float4*)(wp + jj * 32 + k8 * 4);
            s = fmaf(w.x, cp[k8 * 4 + 0], s);
            s = fmaf(w.y, cp[k8 * 4 + 1], s);
            s = fmaf(w.z, cp[k8 * 4 + 2], s);
            s = fmaf(w.w, cp[k8 * 4 + 3], s);
        }
        res[jj] = s;
    }
    ((float4*)UH)[(b * 8192 + e0) >> 2] = make_float4(res[0], res[1], res[2], res[3]);
}

// ---------------------------------------------------------------------------
// K8b: 3-iter aspect routing on LDS-resident UH. grid 4, 256 thr. [proven]
__global__ void k_route(const float* __restrict__ UH, float* __restrict__ VA)
{
    const int b = blockIdx.x;
    const int t = threadIdx.x;
    __shared__ float uh[8192], ba[256], cc[256], sbuf[512], msc[32];
#pragma unroll
    for (int i = 0; i < 8; ++i)
        ((float4*)uh)[i * 256 + t] = ((const float4*)UH)[b * 2048 + i * 256 + t];
    ba[t] = 0.f;
    __syncthreads();
    for (int it = 0; it < 3; ++it) {
        if (t < 16) {
            float mx = -1e30f;
            for (int j = 0; j < 16; ++j) mx = fmaxf(mx, ba[t * 16 + j]);
            float sum = 0.f;
            for (int j = 0; j < 16; ++j) { cc[t * 16 + j] = expf(ba[t * 16 + j] - mx); sum += cc[t * 16 + j]; }
            const float inv = 1.f / sum;
            for (int j = 0; j < 16; ++j) cc[t * 16 + j] *= inv;
        }
        __syncthreads();
        for (int h = 0; h < 2; ++h) {
            const int e = h * 256 + t;
            const int j = e >> 5;
            float s = 0.f;
            for (int i = 0; i < 16; ++i) s = fmaf(cc[i * 16 + j], uh[i * 512 + e], s);
            sbuf[e] = s;
        }
        __syncthreads();
        if (t < 32) {
            float mg = 0.f;
            for (int j = 0; j < 16; ++j) { const float x = sbuf[j * 32 + t]; mg = fmaf(x, x, mg); }
            msc[t] = sqrtf(mg) / (1.f + mg);
        }
        __syncthreads();
        for (int h = 0; h < 2; ++h) {
            const int e = h * 256 + t;
            sbuf[e] *= msc[e & 31];
        }
        __syncthreads();
        if (it < 2) {
            const int i = t >> 4, j = t & 15;
            float s = 0.f;
            for (int u = 0; u < 32; ++u) s = fmaf(uh[i * 512 + j * 32 + u], sbuf[j * 32 + u], s);
            ba[t] += s;
            __syncthreads();
        }
    }
    VA[b * 512 + t] = sbuf[t];
    VA[b * 512 + 256 + t] = sbuf[256 + t];
}

// ---------------------------------------------------------------------------
// K9: broadcast VA to all 512 rows per example  [proven]
__global__ void k_out(const float* __restrict__ VA, float* __restrict__ out)
{
    const int idx = blockIdx.x * 256 + threadIdx.x;
    const int b = idx >> 16;
    const int jv4 = idx & 127;
    ((float4*)out)[idx] = ((const float4*)VA)[b * 128 + jv4];
}

// ---------------------------------------------------------------------------
extern "C" void kernel_launch(void* const* d_in, const int* in_sizes, int n_in,
                              void* d_out, int out_size, void* d_ws, size_t ws_size,
                              hipStream_t stream)
{
    const float* X   = (const float*)d_in[0];
    // d_in[1] = hidden — provably unused (softmax shift-invariance kills it)
    const float* Wp  = (const float*)d_in[2];
    const float* bp  = (const float*)d_in[3];
    const float* Wg  = (const float*)d_in[4];
    const float* Wa  = (const float*)d_in[5];
    const float* Wsp = (const float*)d_in[6];
    float* out = (float*)d_out;
    float* ws = (float*)d_ws;

    float* U   = ws + OFF_U;
    float* S   = ws + OFF_S;
    float* SSp = ws + OFF_SSP;
    float* Bgp = ws + OFF_BGP;
    float* Gp  = ws + OFF_GP;
    float* VA  = ws + OFF_VA;
    float* MS  = ws + OFF_MS;
    float* UH  = ws + OFF_UH;
    float* Wgr = ws + OFF_WGR;

    // NO memset: SSp/Bgp/Gp are pure-store partial buffers (no zero-init).

    // primary GEMM (full-K fused, + z==4 one-time Wg reorder)
    k_primaryF<<<dim3(2, 16, 5), 256, 0, stream>>>(X, Wp, bp, U, SSp, Wg, Wgr);

    // routing: iter0 cls = softmax(0) = 1/16 exactly (bg0=1)
    k_smatmulM2<<<dim3(16, 4, 4), 256, 0, stream>>>(U, SSp, Bgp, Wgr, S, MS, nullptr, 1);
    k_tbu2<<<dim3(8, 16, 4), 256, 0, stream>>>(U, SSp, S, MS, Wg, Bgp, 1);
    k_smatmulM2<<<dim3(16, 4, 4), 256, 0, stream>>>(U, SSp, Bgp, Wgr, S, MS, nullptr, 0);
    k_tbu2<<<dim3(8, 16, 4), 256, 0, stream>>>(U, SSp, S, MS, Wg, Bgp, 0);
    k_smatmulM2<<<dim3(16, 4, 4), 256, 0, stream>>>(U, SSp, Bgp, Wgr, S, nullptr, Gp, 0);

    k_uhat2<<<dim3(8, 4), 256, 0, stream>>>(Gp, Wa, Wsp, UH);
    k_route<<<4, 256, 0, stream>>>(UH, VA);
    k_out<<<1024, 256, 0, stream>>>(VA, out);
}

// Round 7
// 196.260 us; speedup vs baseline: 1.1752x; 1.1752x over previous
//
#include <hip/hip_runtime.h>
#include <math.h>

// Problem constants: B=4, GL=4, GF=128, N=1024, CS=32, CN=16, NA=16, S=512
//
// Flat views (fp32, per b):
//  X   : [512 k][1024 n]
//  U   : [128 c][1024 n] ; P2 view: [1024 m][128 q], q=k*32+i, scale sc[l], l=m>>8
//  S   : [1024 m][512 ju]  (UNsquashed)   ju=j*32+u
//  MS  : [1024 m][32 u]    squash scale per (m,u)
//  UH  : [8192]            u_hat for aspect routing, e = i*512 + j*32 + u
//  WGR : [128 q][32 u][16 j] reordered Wg (built once)
//  SSp : [b][l][8 cg] partial sum-of-squares (pure stores, no zero-init)
//  Bgp : [b][16 mc][8 jt][64] partial b-logits (tbu stores iter0, adds after)
//  Gp  : [b][16 mt][512] partial G (smatmul #3 stores; uhat sums)

static constexpr int OFF_U   = 0;          // 524288
static constexpr int OFF_S   = 524288;     // 2097152 -> end 2621440 (Upart[4] alias pre-reduceU)
static constexpr int OFF_SSP = 2621440;    // 256 (128 used)
static constexpr int OFF_BGP = 2621696;    // 32768 -> end 2654464
static constexpr int OFF_GP  = 2654464;    // 32768 -> end 2687232
static constexpr int OFF_VA  = 2687232;    // 2048  -> end 2689280
static constexpr int OFF_MS  = 2689280;    // 131072 -> end 2820352
static constexpr int OFF_UH  = 2820352;    // 32768 -> end 2853120
static constexpr int OFF_WGR = 2853120;    // 65536 -> end 2918656 (< 2922512 proven bound)

// ---------------------------------------------------------------------------
// K1a: partial U over K-window of 128 (z<16)  [proven, 512 blocks]
//      + z==16: one-time Wg reorder into WGR (32 blocks ride free)
__global__ void k_primary_part(const float* __restrict__ X, const float* __restrict__ Wp,
                               float* __restrict__ Upart,
                               const float* __restrict__ Wg, float* __restrict__ Wgr)
{
    __shared__ float Wt[128 * 68];
    const int t = threadIdx.x;
    if (blockIdx.z == 16) {
        // Wgr[q*512 + u*16 + j] = Wg[((i*16+j)*32+u)*4 + kk], q = kk*32+i
        const int blk = blockIdx.x * 16 + blockIdx.y;       // 0..31
#pragma unroll
        for (int r = 0; r < 8; ++r) {
            const int e = blk * 2048 + r * 256 + t;         // 0..65535
            const int q = e >> 9, rem = e & 511;
            const int u = rem >> 4, j = rem & 15;
            const int i = q & 31, kk = q >> 5;
            Wgr[e] = Wg[((i * 16 + j) * 32 + u) * 4 + kk];
        }
        return;
    }
    const int ct = blockIdx.x, nt = blockIdx.y;
    const int b = blockIdx.z >> 2, ks = blockIdx.z & 3;
    const int tn = t & 15, tc = t >> 4;
    const int c0 = ct * 64, n0 = nt * 64;
#pragma unroll
    for (int i = 0; i < 8; ++i) {
        const int idx = t + i * 256;
        const int c = idx >> 5, k4 = idx & 31;
        const float4 wv = *(const float4*)&Wp[(size_t)(c0 + c) * 512 + ks * 128 + k4 * 4];
        Wt[(k4 * 4 + 0) * 68 + c] = wv.x;
        Wt[(k4 * 4 + 1) * 68 + c] = wv.y;
        Wt[(k4 * 4 + 2) * 68 + c] = wv.z;
        Wt[(k4 * 4 + 3) * 68 + c] = wv.w;
    }
    __syncthreads();
    float acc[4][4] = {};
    const float* Xp = X + (size_t)b * 524288 + (size_t)(ks * 128) * 1024 + n0 + tn * 4;
#pragma unroll 4
    for (int k = 0; k < 128; ++k) {
        const float4 xv = *(const float4*)(Xp + (size_t)k * 1024);
        const float4 wv = *(const float4*)&Wt[k * 68 + tc * 4];
        const float w[4] = {wv.x, wv.y, wv.z, wv.w};
        const float x[4] = {xv.x, xv.y, xv.z, xv.w};
#pragma unroll
        for (int ci = 0; ci < 4; ++ci)
#pragma unroll
            for (int ni = 0; ni < 4; ++ni)
                acc[ci][ni] = fmaf(w[ci], x[ni], acc[ci][ni]);
    }
    float* up = Upart + (size_t)ks * 524288 + (size_t)b * 131072;
#pragma unroll
    for (int ci = 0; ci < 4; ++ci)
        *(float4*)&up[(size_t)(c0 + tc * 4 + ci) * 1024 + n0 + tn * 4] =
            make_float4(acc[ci][0], acc[ci][1], acc[ci][2], acc[ci][3]);
}

// ---------------------------------------------------------------------------
// K1b: U = sum_ks Upart[ks] + bp; SSp partial store (no atomics/zero-init).
// grid 128 (b 4 x cg 32).  [proven core; epilogue -> pure store]
__global__ void k_reduceU(const float* __restrict__ Upart, const float* __restrict__ bp,
                          float* __restrict__ U, float* __restrict__ SSp)
{
    __shared__ float red[256];
    const int blk = blockIdx.x, t = threadIdx.x;
    const int b = blk >> 5, cg = blk & 31;
    float ssq = 0.f;
#pragma unroll
    for (int i = 0; i < 4; ++i) {
        const int c = cg * 4 + i;
        const int f4 = b * 32768 + c * 256 + t;
        float4 s = ((const float4*)Upart)[f4];
#pragma unroll
        for (int ks = 1; ks < 4; ++ks) {
            const float4 p = ((const float4*)Upart)[ks * 131072 + f4];
            s.x += p.x; s.y += p.y; s.z += p.z; s.w += p.w;
        }
        const float bv = bp[c];
        s.x += bv; s.y += bv; s.z += bv; s.w += bv;
        ssq = fmaf(s.x, s.x, ssq); ssq = fmaf(s.y, s.y, ssq);
        ssq = fmaf(s.z, s.z, ssq); ssq = fmaf(s.w, s.w, ssq);
        ((float4*)U)[f4] = s;
    }
    red[t] = ssq;
    __syncthreads();
    for (int s = 128; s > 0; s >>= 1) {
        if (t < s) red[t] += red[t + s];
        __syncthreads();
    }
    if (t == 0) SSp[(b * 4 + (cg >> 3)) * 8 + (cg & 7)] = red[0];
}

// ---------------------------------------------------------------------------
// K4 "smatmulM2": S = (P2*sc) @ (cls o Wg), u-sliced; MS in-block (iters 0,1)
// or Gp partial store (iter 2). cls from Bgp partial sums (bg0: exact 1/16).
// grid (16 mt, 4 us, 4 b), 256 thr, thread tile 4m x 8j.  [proven r5/r6]
__global__ __launch_bounds__(256) void k_smatmulM2(
    const float* __restrict__ U, const float* __restrict__ SSp,
    const float* __restrict__ Bgp, const float* __restrict__ Wgr,
    float* __restrict__ S, float* __restrict__ MS, float* __restrict__ Gp,
    const int bg0)
{
    __shared__ __align__(16) float Pt[64 * 68];    // [qL][m]
    __shared__ __align__(16) float Ct[64 * 160];   // [qL][cpad]
    __shared__ float cls[512];
    __shared__ float bgs[512];
    __shared__ float gacc[128];
    const int mt = blockIdx.x, us = blockIdx.y, b = blockIdx.z;
    const int t = threadIdx.x;
    const int tm = t >> 4;
    const int uu = t & 7, jh = (t >> 3) & 1;
    const int m0 = mt * 64;

    if (bg0) {
        cls[t] = 0.0625f;            // softmax(0) == 1/16 exactly
        cls[t + 256] = 0.0625f;
    } else {
#pragma unroll
        for (int h = 0; h < 2; ++h) {
            const int p = t + h * 256;               // (i,j): i=p>>4, j=p&15
            const int i = p >> 4, j = p & 15;
            float s = 0.f;
#pragma unroll 4
            for (int mc = 0; mc < 16; ++mc)
                s += Bgp[((b * 16 + mc) * 8 + (j >> 1)) * 64 + i * 2 + (j & 1)];
            bgs[p] = s * (1.f / 1024.f);
        }
        __syncthreads();
        if (t < 32) {
            float vals[16];
            float mx = -1e30f;
            for (int j = 0; j < 16; ++j) { vals[j] = bgs[t * 16 + j]; mx = fmaxf(mx, vals[j]); }
            float sum = 0.f;
            for (int j = 0; j < 16; ++j) { vals[j] = expf(vals[j] - mx); sum += vals[j]; }
            const float inv = 1.f / sum;
            for (int j = 0; j < 16; ++j) cls[t * 16 + j] = vals[j] * inv;
        }
    }
    if (Gp != nullptr && t < 128) gacc[t] = 0.f;
    // squash scale: uniform 8-float sum of SS partials
    float ssum = 0.f;
#pragma unroll
    for (int i = 0; i < 8; ++i) ssum += SSp[(b * 4 + (mt >> 2)) * 8 + i];
    const float sc = sqrtf(ssum) / (1.f + ssum);
    float acc[4][8] = {};
    const float* Ub = U + (size_t)b * 131072 + (size_t)m0 * 128;
    __syncthreads();

    for (int kc = 0; kc < 2; ++kc) {
#pragma unroll
        for (int it = 0; it < 4; ++it) {
            const int x = t + it * 256;           // 0..1023
            const int m = x & 63, q4 = x >> 6;    // q4 0..15
            const float4 v = *(const float4*)&Ub[(size_t)m * 128 + kc * 64 + q4 * 4];
            Pt[(q4 * 4 + 0) * 68 + m] = v.x * sc;
            Pt[(q4 * 4 + 1) * 68 + m] = v.y * sc;
            Pt[(q4 * 4 + 2) * 68 + m] = v.z * sc;
            Pt[(q4 * 4 + 3) * 68 + m] = v.w * sc;
        }
#pragma unroll
        for (int it = 0; it < 8; ++it) {
            const int x = t + it * 256;           // 0..2047
            const int c4 = (x & 31) * 4, qL = x >> 5;
            const int q = kc * 64 + qL;
            const int i = q & 31;
            const int j0 = c4 & 15;
            const float4 w = *(const float4*)&Wgr[(size_t)q * 512 + us * 128 + c4];
            const int cp = qL * 160 + c4 + ((c4 >> 4) << 2);
            Ct[cp + 0] = cls[i * 16 + j0 + 0] * w.x;
            Ct[cp + 1] = cls[i * 16 + j0 + 1] * w.y;
            Ct[cp + 2] = cls[i * 16 + j0 + 2] * w.z;
            Ct[cp + 3] = cls[i * 16 + j0 + 3] * w.w;
        }
        __syncthreads();
        const int cbase = uu * 20 + jh * 8;       // cpad of c = uu*16 + jh*8
#pragma unroll 4
        for (int qL = 0; qL < 64; ++qL) {
            const float4 p4 = *(const float4*)&Pt[qL * 68 + tm * 4];
            const float4 ca = *(const float4*)&Ct[qL * 160 + cbase];
            const float4 cb = *(const float4*)&Ct[qL * 160 + cbase + 4];
            const float pm[4] = {p4.x, p4.y, p4.z, p4.w};
            const float cj[8] = {ca.x, ca.y, ca.z, ca.w, cb.x, cb.y, cb.z, cb.w};
#pragma unroll
            for (int mm = 0; mm < 4; ++mm)
#pragma unroll
                for (int jj = 0; jj < 8; ++jj)
                    acc[mm][jj] = fmaf(pm[mm], cj[jj], acc[mm][jj]);
        }
        __syncthreads();
    }

    // store S: ju = (jh*8+jj)*32 + us*8 + uu
#pragma unroll
    for (int mm = 0; mm < 4; ++mm) {
        float* Sp = S + (size_t)b * 524288 + (size_t)(m0 + tm * 4 + mm) * 512 + us * 8 + uu;
#pragma unroll
        for (int jj = 0; jj < 8; ++jj)
            Sp[(jh * 8 + jj) * 32] = acc[mm][jj];
    }

    if (Gp == nullptr) {
        // MS[m][u] from full-j sum of squares (jh pair via shfl)
#pragma unroll
        for (int mm = 0; mm < 4; ++mm) {
            float msq = 0.f;
#pragma unroll
            for (int jj = 0; jj < 8; ++jj) msq = fmaf(acc[mm][jj], acc[mm][jj], msq);
            msq += __shfl_xor(msq, 8);
            if (jh == 0)
                MS[b * 32768 + (m0 + tm * 4 + mm) * 32 + us * 8 + uu] =
                    sqrtf(msq) / (1.f + msq);
        }
    } else {
        // last iter: Gp[b][mt][ju] = (1/1024) sum_{m in tile} S*msc  (pure store)
        float part[8];
#pragma unroll
        for (int jj = 0; jj < 8; ++jj) part[jj] = 0.f;
#pragma unroll
        for (int mm = 0; mm < 4; ++mm) {
            float msq = 0.f;
#pragma unroll
            for (int jj = 0; jj < 8; ++jj) msq = fmaf(acc[mm][jj], acc[mm][jj], msq);
            msq += __shfl_xor(msq, 8);
            const float msc = sqrtf(msq) / (1.f + msq);
#pragma unroll
            for (int jj = 0; jj < 8; ++jj) part[jj] = fmaf(acc[mm][jj], msc, part[jj]);
        }
#pragma unroll
        for (int jj = 0; jj < 8; ++jj)
            atomicAdd(&gacc[(jh * 8 + jj) * 8 + uu], part[jj]);
        __syncthreads();
        if (t < 128) {
            const int j = t >> 3, u2 = t & 7;
            Gp[(size_t)(b * 16 + mt) * 512 + j * 32 + us * 8 + u2] =
                gacc[t] * (1.f / 1024.f);
        }
    }
}

// ---------------------------------------------------------------------------
// K6 "tbu2": b-update into Bgp partial slots (first: store, else: add).
// grid (8 jt, 16 mc, 4 b), 256 thr.  [proven]
__global__ void k_tbu2(const float* __restrict__ U, const float* __restrict__ SSp,
                       const float* __restrict__ S, const float* __restrict__ MS,
                       const float* __restrict__ Wg, float* __restrict__ Bgp,
                       const int first)
{
    __shared__ float Ps[64 * 132];   // [m][q], pad 132
    __shared__ float Vs[64 * 68];    // [m][jv], pad 68
    __shared__ float bup[64];        // [i][j_loc]
    const int jt = blockIdx.x, mc = blockIdx.y, b = blockIdx.z;
    const int t = threadIdx.x;
    const int tq = t & 31, tjv = t >> 5;
    const int m0 = mc * 64;
    if (t < 64) bup[t] = 0.f;
    float ssum = 0.f;
#pragma unroll
    for (int i = 0; i < 8; ++i) ssum += SSp[(b * 4 + (mc >> 2)) * 8 + i];
    const float sc = sqrtf(ssum) / (1.f + ssum);
#pragma unroll
    for (int i = 0; i < 8; ++i) {
        const int f4 = t + i * 256;
        const int r = f4 >> 5, q4 = f4 & 31;
        float4 v = *(const float4*)&U[(size_t)b * 131072 + (size_t)(m0 + r) * 128 + q4 * 4];
        v.x *= sc; v.y *= sc; v.z *= sc; v.w *= sc;
        *(float4*)&Ps[r * 132 + q4 * 4] = v;
    }
#pragma unroll
    for (int i = 0; i < 4; ++i) {
        const int f4 = t + i * 256;
        const int r = f4 >> 4, c4 = f4 & 15;
        const int m = m0 + r;
        float4 v = *(const float4*)&S[(size_t)b * 524288 + (size_t)m * 512 + jt * 64 + c4 * 4];
        const int ub = (c4 * 4) & 31;
        const float* msp = MS + b * 32768 + m * 32;
        v.x *= msp[ub + 0]; v.y *= msp[ub + 1]; v.z *= msp[ub + 2]; v.w *= msp[ub + 3];
        *(float4*)&Vs[r * 68 + c4 * 4] = v;
    }
    __syncthreads();
    float acc[4][8] = {};
#pragma unroll 2
    for (int m = 0; m < 64; ++m) {
        const float4 p4 = *(const float4*)&Ps[m * 132 + tq * 4];
        const float4 va = *(const float4*)&Vs[m * 68 + tjv * 8];
        const float4 vb = *(const float4*)&Vs[m * 68 + tjv * 8 + 4];
        const float pv[4] = {p4.x, p4.y, p4.z, p4.w};
        const float vv[8] = {va.x, va.y, va.z, va.w, vb.x, vb.y, vb.z, vb.w};
#pragma unroll
        for (int qi = 0; qi < 4; ++qi)
#pragma unroll
            for (int ji = 0; ji < 8; ++ji)
                acc[qi][ji] = fmaf(pv[qi], vv[ji], acc[qi][ji]);
    }
    const int k = tq >> 3;
    const int j_loc = tjv >> 2;
    const int j = jt * 2 + j_loc;
    const int u0 = (tjv & 3) * 8;
#pragma unroll
    for (int qi = 0; qi < 4; ++qi) {
        const int i = (tq & 7) * 4 + qi;
        const float* wp = Wg + ((i * 16 + j) * 32) * 4 + k;
        float s = 0.f;
#pragma unroll
        for (int ji = 0; ji < 8; ++ji)
            s = fmaf(wp[(u0 + ji) * 4], acc[qi][ji], s);
        s += __shfl_xor(s, 8);
        s += __shfl_xor(s, 16);
        s += __shfl_xor(s, 32);
        if ((t & 56) == 0) atomicAdd(&bup[i * 2 + j_loc], s);
    }
    __syncthreads();
    if (t < 64) {
        float* slot = &Bgp[((b * 16 + mc) * 8 + jt) * 64 + t];
        if (first) *slot = bup[t];
        else       *slot += bup[t];
    }
}

// ---------------------------------------------------------------------------
// K8a "uhat2": attention + aspect u_hat; G from Gp partials. grid (8, 4 b). [proven r6]
__global__ void k_uhat2(const float* __restrict__ Gp, const float* __restrict__ Wa,
                        const float* __restrict__ Ws, float* __restrict__ UH)
{
    const int b = blockIdx.y;
    const int t = threadIdx.x;
    __shared__ float g[512], cond[512], score[16], red[16];
    float g0 = 0.f, g1 = 0.f;
#pragma unroll 4
    for (int mt = 0; mt < 16; ++mt) {
        const float* gp = Gp + (size_t)(b * 16 + mt) * 512;
        g0 += gp[t];
        g1 += gp[t + 256];
    }
    g[t] = g0;
    g[t + 256] = g1;
    __syncthreads();
    if (t < 16) {
        float s = 0.f;
        for (int u = 0; u < 32; ++u) s = fmaf(g[t * 32 + u], Wa[u], s);
        red[t] = s;
    }
    __syncthreads();
    if (t == 0) {
        float mx = -1e30f;
        for (int j = 0; j < 16; ++j) mx = fmaxf(mx, red[j]);
        float sum = 0.f;
        for (int j = 0; j < 16; ++j) { score[j] = expf(red[j] - mx); sum += score[j]; }
        const float inv = 1.f / sum;
        for (int j = 0; j < 16; ++j) score[j] *= inv;
    }
    __syncthreads();
    cond[t] = g[t] * score[t >> 5];
    cond[t + 256] = g[t + 256] * score[(t + 256) >> 5];
    __syncthreads();
    const int e0 = blockIdx.x * 1024 + t * 4;
    const int i = e0 >> 9;
    const float* cp = cond + i * 32;
    const float* wp = Ws + (size_t)e0 * 32;
    float res[4];
#pragma unroll
    for (int jj = 0; jj < 4; ++jj) {
        float s = 0.f;
#pragma unroll
        for (int k8 = 0; k8 < 8; ++k8) {
            const float4 w = *(const float4*)(wp + jj * 32 + k8 * 4);
            s = fmaf(w.x, cp[k8 * 4 + 0], s);
            s = fmaf(w.y, cp[k8 * 4 + 1], s);
            s = fmaf(w.z, cp[k8 * 4 + 2], s);
            s = fmaf(w.w, cp[k8 * 4 + 3], s);
        }
        res[jj] = s;
    }
    ((float4*)UH)[(b * 8192 + e0) >> 2] = make_float4(res[0], res[1], res[2], res[3]);
}

// ---------------------------------------------------------------------------
// K8b: 3-iter aspect routing on LDS-resident UH. grid 4, 256 thr. [proven]
__global__ void k_route(const float* __restrict__ UH, float* __restrict__ VA)
{
    const int b = blockIdx.x;
    const int t = threadIdx.x;
    __shared__ float uh[8192], ba[256], cc[256], sbuf[512], msc[32];
#pragma unroll
    for (int i = 0; i < 8; ++i)
        ((float4*)uh)[i * 256 + t] = ((const float4*)UH)[b * 2048 + i * 256 + t];
    ba[t] = 0.f;
    __syncthreads();
    for (int it = 0; it < 3; ++it) {
        if (t < 16) {
            float mx = -1e30f;
            for (int j = 0; j < 16; ++j) mx = fmaxf(mx, ba[t * 16 + j]);
            float sum = 0.f;
            for (int j = 0; j < 16; ++j) { cc[t * 16 + j] = expf(ba[t * 16 + j] - mx); sum += cc[t * 16 + j]; }
            const float inv = 1.f / sum;
            for (int j = 0; j < 16; ++j) cc[t * 16 + j] *= inv;
        }
        __syncthreads();
        for (int h = 0; h < 2; ++h) {
            const int e = h * 256 + t;
            const int j = e >> 5;
            float s = 0.f;
            for (int i = 0; i < 16; ++i) s = fmaf(cc[i * 16 + j], uh[i * 512 + e], s);
            sbuf[e] = s;
        }
        __syncthreads();
        if (t < 32) {
            float mg = 0.f;
            for (int j = 0; j < 16; ++j) { const float x = sbuf[j * 32 + t]; mg = fmaf(x, x, mg); }
            msc[t] = sqrtf(mg) / (1.f + mg);
        }
        __syncthreads();
        for (int h = 0; h < 2; ++h) {
            const int e = h * 256 + t;
            sbuf[e] *= msc[e & 31];
        }
        __syncthreads();
        if (it < 2) {
            const int i = t >> 4, j = t & 15;
            float s = 0.f;
            for (int u = 0; u < 32; ++u) s = fmaf(uh[i * 512 + j * 32 + u], sbuf[j * 32 + u], s);
            ba[t] += s;
            __syncthreads();
        }
    }
    VA[b * 512 + t] = sbuf[t];
    VA[b * 512 + 256 + t] = sbuf[256 + t];
}

// ---------------------------------------------------------------------------
// K9: broadcast VA to all 512 rows per example  [proven]
__global__ void k_out(const float* __restrict__ VA, float* __restrict__ out)
{
    const int idx = blockIdx.x * 256 + threadIdx.x;
    const int b = idx >> 16;
    const int jv4 = idx & 127;
    ((float4*)out)[idx] = ((const float4*)VA)[b * 128 + jv4];
}

// ---------------------------------------------------------------------------
extern "C" void kernel_launch(void* const* d_in, const int* in_sizes, int n_in,
                              void* d_out, int out_size, void* d_ws, size_t ws_size,
                              hipStream_t stream)
{
    const float* X   = (const float*)d_in[0];
    // d_in[1] = hidden — provably unused (softmax shift-invariance kills it)
    const float* Wp  = (const float*)d_in[2];
    const float* bp  = (const float*)d_in[3];
    const float* Wg  = (const float*)d_in[4];
    const float* Wa  = (const float*)d_in[5];
    const float* Wsp = (const float*)d_in[6];
    float* out = (float*)d_out;
    float* ws = (float*)d_ws;

    float* U   = ws + OFF_U;
    float* S   = ws + OFF_S;     // Upart[4] alias before k_reduceU
    float* SSp = ws + OFF_SSP;
    float* Bgp = ws + OFF_BGP;
    float* Gp  = ws + OFF_GP;
    float* VA  = ws + OFF_VA;
    float* MS  = ws + OFF_MS;
    float* UH  = ws + OFF_UH;
    float* Wgr = ws + OFF_WGR;

    // NO memset: SSp/Bgp/Gp are pure-store partial buffers.

    // primary GEMM partials (512 blocks) + z==16 one-time Wg reorder
    k_primary_part<<<dim3(2, 16, 17), 256, 0, stream>>>(X, Wp, S, Wg, Wgr);
    k_reduceU<<<128, 256, 0, stream>>>(S, bp, U, SSp);

    // routing: iter0 cls = softmax(0) = 1/16 exactly (bg0=1)
    k_smatmulM2<<<dim3(16, 4, 4), 256, 0, stream>>>(U, SSp, Bgp, Wgr, S, MS, nullptr, 1);
    k_tbu2<<<dim3(8, 16, 4), 256, 0, stream>>>(U, SSp, S, MS, Wg, Bgp, 1);
    k_smatmulM2<<<dim3(16, 4, 4), 256, 0, stream>>>(U, SSp, Bgp, Wgr, S, MS, nullptr, 0);
    k_tbu2<<<dim3(8, 16, 4), 256, 0, stream>>>(U, SSp, S, MS, Wg, Bgp, 0);
    k_smatmulM2<<<dim3(16, 4, 4), 256, 0, stream>>>(U, SSp, Bgp, Wgr, S, nullptr, Gp, 0);

    k_uhat2<<<dim3(8, 4), 256, 0, stream>>>(Gp, Wa, Wsp, UH);
    k_route<<<4, 256, 0, stream>>>(UH, VA);
    k_out<<<1024, 256, 0, stream>>>(VA, out);
}

// Round 8
// 195.851 us; speedup vs baseline: 1.1776x; 1.0021x over previous
//
#include <hip/hip_runtime.h>
#include <math.h>

// Problem constants: B=4, GL=4, GF=128, N=1024, CS=32, CN=16, NA=16, S=512
//
// Flat views (fp32, per b):
//  X    : [512 k][1024 n]
//  U    : [128 c][1024 n] ; P2 view: [1024 m][128 q], q=k*32+i, scale sc[l], l=m>>8
//  UH   : [8192]           u_hat for aspect routing, e = i*512 + j*32 + u
//  WGR  : [128 q][32 u][16 j] reordered Wg (built once)
//  SSp  : [b][l][8 cg]     partial sum-of-squares (pure stores)
//  Bgp2 : [b][64 g][512 p] partial b-logits, g = mt*4+us, p = i*16+j
//  Gp   : [b][16 mt][512]  partial G (k_iter LAST stores; uhat sums)
//
// NOTE: S and MS no longer exist in global memory — the smatmul+tbu pair is
// fused into k_iter, which keeps V = S*msc entirely in registers/LDS.

static constexpr int OFF_U    = 0;          // 524288
static constexpr int OFF_UPART= 524288;     // 2097152 (primary partials scratch)
static constexpr int OFF_SSP  = 2621440;    // 256 (128 used)
static constexpr int OFF_BGP2 = 2621696;    // 131072 -> end 2752768
static constexpr int OFF_GP   = 2752768;    // 32768 -> end 2785536
static constexpr int OFF_VA   = 2785536;    // 2048  -> end 2787584
static constexpr int OFF_UH   = 2787584;    // 32768 -> end 2820352
static constexpr int OFF_WGR  = 2820352;    // 65536 -> end 2885888 (< 2922512 proven bound)

// ---------------------------------------------------------------------------
// K1a: partial U over K-window of 128 (z<16)  [proven, 512 blocks]
//      + z==16: one-time Wg reorder into WGR (32 blocks ride free)
__global__ void k_primary_part(const float* __restrict__ X, const float* __restrict__ Wp,
                               float* __restrict__ Upart,
                               const float* __restrict__ Wg, float* __restrict__ Wgr)
{
    __shared__ float Wt[128 * 68];
    const int t = threadIdx.x;
    if (blockIdx.z == 16) {
        // Wgr[q*512 + u*16 + j] = Wg[((i*16+j)*32+u)*4 + kk], q = kk*32+i
        const int blk = blockIdx.x * 16 + blockIdx.y;       // 0..31
#pragma unroll
        for (int r = 0; r < 8; ++r) {
            const int e = blk * 2048 + r * 256 + t;         // 0..65535
            const int q = e >> 9, rem = e & 511;
            const int u = rem >> 4, j = rem & 15;
            const int i = q & 31, kk = q >> 5;
            Wgr[e] = Wg[((i * 16 + j) * 32 + u) * 4 + kk];
        }
        return;
    }
    const int ct = blockIdx.x, nt = blockIdx.y;
    const int b = blockIdx.z >> 2, ks = blockIdx.z & 3;
    const int tn = t & 15, tc = t >> 4;
    const int c0 = ct * 64, n0 = nt * 64;
#pragma unroll
    for (int i = 0; i < 8; ++i) {
        const int idx = t + i * 256;
        const int c = idx >> 5, k4 = idx & 31;
        const float4 wv = *(const float4*)&Wp[(size_t)(c0 + c) * 512 + ks * 128 + k4 * 4];
        Wt[(k4 * 4 + 0) * 68 + c] = wv.x;
        Wt[(k4 * 4 + 1) * 68 + c] = wv.y;
        Wt[(k4 * 4 + 2) * 68 + c] = wv.z;
        Wt[(k4 * 4 + 3) * 68 + c] = wv.w;
    }
    __syncthreads();
    float acc[4][4] = {};
    const float* Xp = X + (size_t)b * 524288 + (size_t)(ks * 128) * 1024 + n0 + tn * 4;
#pragma unroll 4
    for (int k = 0; k < 128; ++k) {
        const float4 xv = *(const float4*)(Xp + (size_t)k * 1024);
        const float4 wv = *(const float4*)&Wt[k * 68 + tc * 4];
        const float w[4] = {wv.x, wv.y, wv.z, wv.w};
        const float x[4] = {xv.x, xv.y, xv.z, xv.w};
#pragma unroll
        for (int ci = 0; ci < 4; ++ci)
#pragma unroll
            for (int ni = 0; ni < 4; ++ni)
                acc[ci][ni] = fmaf(w[ci], x[ni], acc[ci][ni]);
    }
    float* up = Upart + (size_t)ks * 524288 + (size_t)b * 131072;
#pragma unroll
    for (int ci = 0; ci < 4; ++ci)
        *(float4*)&up[(size_t)(c0 + tc * 4 + ci) * 1024 + n0 + tn * 4] =
            make_float4(acc[ci][0], acc[ci][1], acc[ci][2], acc[ci][3]);
}

// ---------------------------------------------------------------------------
// K1b: U = sum_ks Upart[ks] + bp; SSp partial store. grid 128.  [proven]
__global__ void k_reduceU(const float* __restrict__ Upart, const float* __restrict__ bp,
                          float* __restrict__ U, float* __restrict__ SSp)
{
    __shared__ float red[256];
    const int blk = blockIdx.x, t = threadIdx.x;
    const int b = blk >> 5, cg = blk & 31;
    float ssq = 0.f;
#pragma unroll
    for (int i = 0; i < 4; ++i) {
        const int c = cg * 4 + i;
        const int f4 = b * 32768 + c * 256 + t;
        float4 s = ((const float4*)Upart)[f4];
#pragma unroll
        for (int ks = 1; ks < 4; ++ks) {
            const float4 p = ((const float4*)Upart)[ks * 131072 + f4];
            s.x += p.x; s.y += p.y; s.z += p.z; s.w += p.w;
        }
        const float bv = bp[c];
        s.x += bv; s.y += bv; s.z += bv; s.w += bv;
        ssq = fmaf(s.x, s.x, ssq); ssq = fmaf(s.y, s.y, ssq);
        ssq = fmaf(s.z, s.z, ssq); ssq = fmaf(s.w, s.w, ssq);
        ((float4*)U)[f4] = s;
    }
    red[t] = ssq;
    __syncthreads();
    for (int s = 128; s > 0; s >>= 1) {
        if (t < s) red[t] += red[t + s];
        __syncthreads();
    }
    if (t == 0) SSp[(b * 4 + (cg >> 3)) * 8 + (cg & 7)] = red[0];
}

// ---------------------------------------------------------------------------
// K4 "k_iter": ONE kernel per routing iteration = smatmul + (tbu | G).
// grid (16 mt, 4 us, 4 b) = 256 blocks, 256 thr.
//
// Phase 1 (S): acc[4m][8j] = (P2*sc) @ (cls o Wg) for u-slice us  [r7-proven core]
//   thread: tm=t>>4 (m-group), uu=t&7 (u in slice), jh=(t>>3)&1 (j half)
// Phase 2 (squash): msc per (m,u) via jh-pair shfl; V = acc*msc in registers.
// Phase 3 (T, if !last): stage Vs[64m][128jv'] (jv'=j*8+uu) into Ct's LDS;
//   re-stage Pt per kc; T[q][jv'] = sum_m Pt[q][m]*Vs[m][jv'].
//   Thread q-map: qL = tq | tq+32  ->  i = tq, k = 2kc+qi  => every thread owns
//   all 4 k for its i: epilogue needs NO cross-lane reduce, NO atomics.
//   bup[i][j] = sum_{k,u in slice} T * Wgr; single writer per (i,j).
//   Bgp2 partial per (b,mt,us): store (first) or += (else).
// Phase 3' (G, if last): Gp partial store  [r7-proven code].
__global__ __launch_bounds__(256) void k_iter(
    const float* __restrict__ U, const float* __restrict__ SSp,
    float* __restrict__ Bgp2, const float* __restrict__ Wgr,
    float* __restrict__ Gp, const int first, const int last)
{
    __shared__ __align__(16) float Pt[64 * 68];     // [qL][m]
    __shared__ __align__(16) float CtVs[64 * 160];  // Ct [qL][cpad] / later Vs [m][132]
    __shared__ float cls[512];
    __shared__ float bgs[512];
    __shared__ float bup[512];
    __shared__ float gacc[128];
    const int mt = blockIdx.x, us = blockIdx.y, b = blockIdx.z;
    const int t = threadIdx.x;
    const int tm = t >> 4;
    const int uu = t & 7, jh = (t >> 3) & 1;
    const int m0 = mt * 64;

    // ---- cls prologue
    if (first) {
        cls[t] = 0.0625f;            // softmax(0) == 1/16 exactly
        cls[t + 256] = 0.0625f;
    } else {
#pragma unroll
        for (int h = 0; h < 2; ++h) {
            const int p = t + h * 256;
            const float* bp2 = Bgp2 + (size_t)b * 32768 + p;
            float s = 0.f;
#pragma unroll 8
            for (int g = 0; g < 64; ++g) s += bp2[g * 512];
            bgs[p] = s * (1.f / 1024.f);
        }
        __syncthreads();
        if (t < 32) {
            float vals[16];
            float mx = -1e30f;
            for (int j = 0; j < 16; ++j) { vals[j] = bgs[t * 16 + j]; mx = fmaxf(mx, vals[j]); }
            float sum = 0.f;
            for (int j = 0; j < 16; ++j) { vals[j] = expf(vals[j] - mx); sum += vals[j]; }
            const float inv = 1.f / sum;
            for (int j = 0; j < 16; ++j) cls[t * 16 + j] = vals[j] * inv;
        }
    }
    if (last && t < 128) gacc[t] = 0.f;
    float ssum = 0.f;
#pragma unroll
    for (int i = 0; i < 8; ++i) ssum += SSp[(b * 4 + (mt >> 2)) * 8 + i];
    const float sc = sqrtf(ssum) / (1.f + ssum);
    float acc[4][8] = {};
    const float* Ub = U + (size_t)b * 131072 + (size_t)m0 * 128;
    __syncthreads();

    // ---- Phase 1: S  [r7 core, verbatim]
    for (int kc = 0; kc < 2; ++kc) {
#pragma unroll
        for (int it = 0; it < 4; ++it) {
            const int x = t + it * 256;           // 0..1023
            const int m = x & 63, q4 = x >> 6;    // q4 0..15
            const float4 v = *(const float4*)&Ub[(size_t)m * 128 + kc * 64 + q4 * 4];
            Pt[(q4 * 4 + 0) * 68 + m] = v.x * sc;
            Pt[(q4 * 4 + 1) * 68 + m] = v.y * sc;
            Pt[(q4 * 4 + 2) * 68 + m] = v.z * sc;
            Pt[(q4 * 4 + 3) * 68 + m] = v.w * sc;
        }
#pragma unroll
        for (int it = 0; it < 8; ++it) {
            const int x = t + it * 256;           // 0..2047
            const int c4 = (x & 31) * 4, qL = x >> 5;
            const int q = kc * 64 + qL;
            const int i = q & 31;
            const int j0 = c4 & 15;
            const float4 w = *(const float4*)&Wgr[(size_t)q * 512 + us * 128 + c4];
            const int cp = qL * 160 + c4 + ((c4 >> 4) << 2);
            CtVs[cp + 0] = cls[i * 16 + j0 + 0] * w.x;
            CtVs[cp + 1] = cls[i * 16 + j0 + 1] * w.y;
            CtVs[cp + 2] = cls[i * 16 + j0 + 2] * w.z;
            CtVs[cp + 3] = cls[i * 16 + j0 + 3] * w.w;
        }
        __syncthreads();
        const int cbase = uu * 20 + jh * 8;       // cpad of c = uu*16 + jh*8
#pragma unroll 4
        for (int qL = 0; qL < 64; ++qL) {
            const float4 p4 = *(const float4*)&Pt[qL * 68 + tm * 4];
            const float4 ca = *(const float4*)&CtVs[qL * 160 + cbase];
            const float4 cb = *(const float4*)&CtVs[qL * 160 + cbase + 4];
            const float pm[4] = {p4.x, p4.y, p4.z, p4.w};
            const float cj[8] = {ca.x, ca.y, ca.z, ca.w, cb.x, cb.y, cb.z, cb.w};
#pragma unroll
            for (int mm = 0; mm < 4; ++mm)
#pragma unroll
                for (int jj = 0; jj < 8; ++jj)
                    acc[mm][jj] = fmaf(pm[mm], cj[jj], acc[mm][jj]);
        }
        __syncthreads();
    }

    // ---- Phase 2: squash scale per (m,u) — full-j sum via jh-pair shfl
    float msc[4];
#pragma unroll
    for (int mm = 0; mm < 4; ++mm) {
        float msq = 0.f;
#pragma unroll
        for (int jj = 0; jj < 8; ++jj) msq = fmaf(acc[mm][jj], acc[mm][jj], msq);
        msq += __shfl_xor(msq, 8);
        msc[mm] = sqrtf(msq) / (1.f + msq);
    }

    if (last) {
        // ---- Phase 3': Gp partial store  [r7 code]
        float part[8];
#pragma unroll
        for (int jj = 0; jj < 8; ++jj) part[jj] = 0.f;
#pragma unroll
        for (int mm = 0; mm < 4; ++mm)
#pragma unroll
            for (int jj = 0; jj < 8; ++jj) part[jj] = fmaf(acc[mm][jj], msc[mm], part[jj]);
#pragma unroll
        for (int jj = 0; jj < 8; ++jj)
            atomicAdd(&gacc[(jh * 8 + jj) * 8 + uu], part[jj]);
        __syncthreads();
        if (t < 128) {
            const int j = t >> 3, u2 = t & 7;
            Gp[(size_t)(b * 16 + mt) * 512 + j * 32 + us * 8 + u2] =
                gacc[t] * (1.f / 1024.f);
        }
        return;
    }

    // ---- Phase 3: in-block tbu
    // V = acc*msc; stage Vs[m-local][jv'], jv' = j*8+uu = jh*64 + jj*8 + uu
    float* Vs = CtVs;                             // reuse Ct region (64*132 <= 64*160)
#pragma unroll
    for (int mm = 0; mm < 4; ++mm)
#pragma unroll
        for (int jj = 0; jj < 8; ++jj)
            Vs[(tm * 4 + mm) * 132 + jh * 64 + jj * 8 + uu] = acc[mm][jj] * msc[mm];

    const int tq = t & 31, tjv = t >> 5;
    float acc2[4][16] = {};                       // [k][ji], ji = jl*8+uu_e
    for (int kc = 0; kc < 2; ++kc) {
        __syncthreads();                          // Vs visible / Pt free to overwrite
#pragma unroll
        for (int it = 0; it < 4; ++it) {          // re-stage Pt chunk kc
            const int x = t + it * 256;
            const int m = x & 63, q4 = x >> 6;
            const float4 v = *(const float4*)&Ub[(size_t)m * 128 + kc * 64 + q4 * 4];
            Pt[(q4 * 4 + 0) * 68 + m] = v.x * sc;
            Pt[(q4 * 4 + 1) * 68 + m] = v.y * sc;
            Pt[(q4 * 4 + 2) * 68 + m] = v.z * sc;
            Pt[(q4 * 4 + 3) * 68 + m] = v.w * sc;
        }
        __syncthreads();
        // T: q = kc*64 + {tq, tq+32} -> i = tq, k = {2kc, 2kc+1}
#pragma unroll 2
        for (int m = 0; m < 64; ++m) {
            const float p0 = Pt[tq * 68 + m];
            const float p1 = Pt[(tq + 32) * 68 + m];
            const float4 v0 = *(const float4*)&Vs[m * 132 + tjv * 16];
            const float4 v1 = *(const float4*)&Vs[m * 132 + tjv * 16 + 4];
            const float4 v2 = *(const float4*)&Vs[m * 132 + tjv * 16 + 8];
            const float4 v3 = *(const float4*)&Vs[m * 132 + tjv * 16 + 12];
            const float vv[16] = {v0.x, v0.y, v0.z, v0.w, v1.x, v1.y, v1.z, v1.w,
                                  v2.x, v2.y, v2.z, v2.w, v3.x, v3.y, v3.z, v3.w};
#pragma unroll
            for (int ji = 0; ji < 16; ++ji) {
                acc2[2 * kc + 0][ji] = fmaf(p0, vv[ji], acc2[2 * kc + 0][ji]);
                acc2[2 * kc + 1][ji] = fmaf(p1, vv[ji], acc2[2 * kc + 1][ji]);
            }
        }
    }
    // epilogue: bup[i][j] = sum_{k,uu} acc2[k][jl*8+uu] * Wgr[(k*32+i)*512+u*16+j]
    // i = tq, j = tjv*2+jl  — single writer per (i,j), no atomics.
#pragma unroll
    for (int jl = 0; jl < 2; ++jl) {
        const int j = tjv * 2 + jl;
        float s = 0.f;
#pragma unroll
        for (int k = 0; k < 4; ++k) {
            const float* wr = Wgr + (size_t)(k * 32 + tq) * 512 + us * 128 + j;
#pragma unroll
            for (int ue = 0; ue < 8; ++ue)
                s = fmaf(wr[ue * 16], acc2[k][jl * 8 + ue], s);
        }
        bup[tq * 16 + j] = s;
    }
    __syncthreads();
    // Bgp2 partial per (b, mt, us): store (first) or += (later)
    {
        float* base = Bgp2 + (size_t)b * 32768 + (size_t)(mt * 4 + us) * 512;
#pragma unroll
        for (int h = 0; h < 2; ++h) {
            const int p = t + h * 256;
            if (first) base[p] = bup[p];
            else       base[p] += bup[p];
        }
    }
}

// ---------------------------------------------------------------------------
// K8a "uhat2": attention + aspect u_hat; G from Gp partials. grid (8, 4 b). [proven]
__global__ void k_uhat2(const float* __restrict__ Gp, const float* __restrict__ Wa,
                        const float* __restrict__ Ws, float* __restrict__ UH)
{
    const int b = blockIdx.y;
    const int t = threadIdx.x;
    __shared__ float g[512], cond[512], score[16], red[16];
    float g0 = 0.f, g1 = 0.f;
#pragma unroll 4
    for (int mt = 0; mt < 16; ++mt) {
        const float* gp = Gp + (size_t)(b * 16 + mt) * 512;
        g0 += gp[t];
        g1 += gp[t + 256];
    }
    g[t] = g0;
    g[t + 256] = g1;
    __syncthreads();
    if (t < 16) {
        float s = 0.f;
        for (int u = 0; u < 32; ++u) s = fmaf(g[t * 32 + u], Wa[u], s);
        red[t] = s;
    }
    __syncthreads();
    if (t == 0) {
        float mx = -1e30f;
        for (int j = 0; j < 16; ++j) mx = fmaxf(mx, red[j]);
        float sum = 0.f;
        for (int j = 0; j < 16; ++j) { score[j] = expf(red[j] - mx); sum += score[j]; }
        const float inv = 1.f / sum;
        for (int j = 0; j < 16; ++j) score[j] *= inv;
    }
    __syncthreads();
    cond[t] = g[t] * score[t >> 5];
    cond[t + 256] = g[t + 256] * score[(t + 256) >> 5];
    __syncthreads();
    const int e0 = blockIdx.x * 1024 + t * 4;
    const int i = e0 >> 9;
    const float* cp = cond + i * 32;
    const float* wp = Ws + (size_t)e0 * 32;
    float res[4];
#pragma unroll
    for (int jj = 0; jj < 4; ++jj) {
        float s = 0.f;
#pragma unroll
        for (int k8 = 0; k8 < 8; ++k8) {
            const float4 w = *(const float4*)(wp + jj * 32 + k8 * 4);
            s = fmaf(w.x, cp[k8 * 4 + 0], s);
            s = fmaf(w.y, cp[k8 * 4 + 1], s);
            s = fmaf(w.z, cp[k8 * 4 + 2], s);
            s = fmaf(w.w, cp[k8 * 4 + 3], s);
        }
        res[jj] = s;
    }
    ((float4*)UH)[(b * 8192 + e0) >> 2] = make_float4(res[0], res[1], res[2], res[3]);
}

// ---------------------------------------------------------------------------
// K8b: 3-iter aspect routing on LDS-resident UH. grid 4, 256 thr. [proven]
__global__ void k_route(const float* __restrict__ UH, float* __restrict__ VA)
{
    const int b = blockIdx.x;
    const int t = threadIdx.x;
    __shared__ float uh[8192], ba[256], cc[256], sbuf[512], msc[32];
#pragma unroll
    for (int i = 0; i < 8; ++i)
        ((float4*)uh)[i * 256 + t] = ((const float4*)UH)[b * 2048 + i * 256 + t];
    ba[t] = 0.f;
    __syncthreads();
    for (int it = 0; it < 3; ++it) {
        if (t < 16) {
            float mx = -1e30f;
            for (int j = 0; j < 16; ++j) mx = fmaxf(mx, ba[t * 16 + j]);
            float sum = 0.f;
            for (int j = 0; j < 16; ++j) { cc[t * 16 + j] = expf(ba[t * 16 + j] - mx); sum += cc[t * 16 + j]; }
            const float inv = 1.f / sum;
            for (int j = 0; j < 16; ++j) cc[t * 16 + j] *= inv;
        }
        __syncthreads();
        for (int h = 0; h < 2; ++h) {
            const int e = h * 256 + t;
            const int j = e >> 5;
            float s = 0.f;
            for (int i = 0; i < 16; ++i) s = fmaf(cc[i * 16 + j], uh[i * 512 + e], s);
            sbuf[e] = s;
        }
        __syncthreads();
        if (t < 32) {
            float mg = 0.f;
            for (int j = 0; j < 16; ++j) { const float x = sbuf[j * 32 + t]; mg = fmaf(x, x, mg); }
            msc[t] = sqrtf(mg) / (1.f + mg);
        }
        __syncthreads();
        for (int h = 0; h < 2; ++h) {
            const int e = h * 256 + t;
            sbuf[e] *= msc[e & 31];
        }
        __syncthreads();
        if (it < 2) {
            const int i = t >> 4, j = t & 15;
            float s = 0.f;
            for (int u = 0; u < 32; ++u) s = fmaf(uh[i * 512 + j * 32 + u], sbuf[j * 32 + u], s);
            ba[t] += s;
            __syncthreads();
        }
    }
    VA[b * 512 + t] = sbuf[t];
    VA[b * 512 + 256 + t] = sbuf[256 + t];
}

// ---------------------------------------------------------------------------
// K9: broadcast VA to all 512 rows per example  [proven]
__global__ void k_out(const float* __restrict__ VA, float* __restrict__ out)
{
    const int idx = blockIdx.x * 256 + threadIdx.x;
    const int b = idx >> 16;
    const int jv4 = idx & 127;
    ((float4*)out)[idx] = ((const float4*)VA)[b * 128 + jv4];
}

// ---------------------------------------------------------------------------
extern "C" void kernel_launch(void* const* d_in, const int* in_sizes, int n_in,
                              void* d_out, int out_size, void* d_ws, size_t ws_size,
                              hipStream_t stream)
{
    const float* X   = (const float*)d_in[0];
    // d_in[1] = hidden — provably unused (softmax shift-invariance kills it)
    const float* Wp  = (const float*)d_in[2];
    const float* bp  = (const float*)d_in[3];
    const float* Wg  = (const float*)d_in[4];
    const float* Wa  = (const float*)d_in[5];
    const float* Wsp = (const float*)d_in[6];
    float* out = (float*)d_out;
    float* ws = (float*)d_ws;

    float* U    = ws + OFF_U;
    float* Up   = ws + OFF_UPART;
    float* SSp  = ws + OFF_SSP;
    float* Bgp2 = ws + OFF_BGP2;
    float* Gp   = ws + OFF_GP;
    float* VA   = ws + OFF_VA;
    float* UH   = ws + OFF_UH;
    float* Wgr  = ws + OFF_WGR;

    // primary GEMM partials (512 blocks) + z==16 one-time Wg reorder
    k_primary_part<<<dim3(2, 16, 17), 256, 0, stream>>>(X, Wp, Up, Wg, Wgr);
    k_reduceU<<<128, 256, 0, stream>>>(Up, bp, U, SSp);

    // routing: one kernel per iteration (smatmul + tbu fused; last does G)
    k_iter<<<dim3(16, 4, 4), 256, 0, stream>>>(U, SSp, Bgp2, Wgr, nullptr, 1, 0);
    k_iter<<<dim3(16, 4, 4), 256, 0, stream>>>(U, SSp, Bgp2, Wgr, nullptr, 0, 0);
    k_iter<<<dim3(16, 4, 4), 256, 0, stream>>>(U, SSp, Bgp2, Wgr, Gp, 0, 1);

    k_uhat2<<<dim3(8, 4), 256, 0, stream>>>(Gp, Wa, Wsp, UH);
    k_route<<<4, 256, 0, stream>>>(UH, VA);
    k_out<<<1024, 256, 0, stream>>>(VA, out);
}

// Round 9
// 191.038 us; speedup vs baseline: 1.2073x; 1.0252x over previous
//
#include <hip/hip_runtime.h>
#include <math.h>

// Problem constants: B=4, GL=4, GF=128, N=1024, CS=32, CN=16, NA=16, S=512
//
// Flat views (fp32, per b):
//  X    : [512 k][1024 n]
//  U    : [128 c][1024 n] ; P2 view: [1024 m][128 q], q=k*32+i, scale sc[l], l=m>>8
//  UH   : [8192]           u_hat for aspect routing, e = i*512 + j*32 + u
//  WGR  : [128 q][32 u][16 j] reordered Wg (built once)
//  SSp  : [b][l][8 cg]     partial sum-of-squares (pure stores)
//  Bgp2 : [b][64 g][512 p] partial b-logits, g = mt*4+us, p = i*16+j
//  Gp   : [b][16 mt][512]  partial G (k_iter LAST stores; uhat sums)

static constexpr int OFF_U    = 0;          // 524288
static constexpr int OFF_UPART= 524288;     // 2097152 (primary partials scratch)
static constexpr int OFF_SSP  = 2621440;    // 256 (128 used)
static constexpr int OFF_BGP2 = 2621696;    // 131072 -> end 2752768
static constexpr int OFF_GP   = 2752768;    // 32768 -> end 2785536
static constexpr int OFF_UH   = 2787584;    // 32768 -> end 2820352
static constexpr int OFF_WGR  = 2820352;    // 65536 -> end 2885888 (< 2922512 proven bound)

// ---------------------------------------------------------------------------
// K1a: partial U over K-window of 128 (z<16)  [proven, 512 blocks]
//      + z==16: one-time Wg reorder into WGR (32 blocks ride free)
__global__ void k_primary_part(const float* __restrict__ X, const float* __restrict__ Wp,
                               float* __restrict__ Upart,
                               const float* __restrict__ Wg, float* __restrict__ Wgr)
{
    __shared__ float Wt[128 * 68];
    const int t = threadIdx.x;
    if (blockIdx.z == 16) {
        // Wgr[q*512 + u*16 + j] = Wg[((i*16+j)*32+u)*4 + kk], q = kk*32+i
        const int blk = blockIdx.x * 16 + blockIdx.y;       // 0..31
#pragma unroll
        for (int r = 0; r < 8; ++r) {
            const int e = blk * 2048 + r * 256 + t;         // 0..65535
            const int q = e >> 9, rem = e & 511;
            const int u = rem >> 4, j = rem & 15;
            const int i = q & 31, kk = q >> 5;
            Wgr[e] = Wg[((i * 16 + j) * 32 + u) * 4 + kk];
        }
        return;
    }
    const int ct = blockIdx.x, nt = blockIdx.y;
    const int b = blockIdx.z >> 2, ks = blockIdx.z & 3;
    const int tn = t & 15, tc = t >> 4;
    const int c0 = ct * 64, n0 = nt * 64;
#pragma unroll
    for (int i = 0; i < 8; ++i) {
        const int idx = t + i * 256;
        const int c = idx >> 5, k4 = idx & 31;
        const float4 wv = *(const float4*)&Wp[(size_t)(c0 + c) * 512 + ks * 128 + k4 * 4];
        Wt[(k4 * 4 + 0) * 68 + c] = wv.x;
        Wt[(k4 * 4 + 1) * 68 + c] = wv.y;
        Wt[(k4 * 4 + 2) * 68 + c] = wv.z;
        Wt[(k4 * 4 + 3) * 68 + c] = wv.w;
    }
    __syncthreads();
    float acc[4][4] = {};
    const float* Xp = X + (size_t)b * 524288 + (size_t)(ks * 128) * 1024 + n0 + tn * 4;
#pragma unroll 4
    for (int k = 0; k < 128; ++k) {
        const float4 xv = *(const float4*)(Xp + (size_t)k * 1024);
        const float4 wv = *(const float4*)&Wt[k * 68 + tc * 4];
        const float w[4] = {wv.x, wv.y, wv.z, wv.w};
        const float x[4] = {xv.x, xv.y, xv.z, xv.w};
#pragma unroll
        for (int ci = 0; ci < 4; ++ci)
#pragma unroll
            for (int ni = 0; ni < 4; ++ni)
                acc[ci][ni] = fmaf(w[ci], x[ni], acc[ci][ni]);
    }
    float* up = Upart + (size_t)ks * 524288 + (size_t)b * 131072;
#pragma unroll
    for (int ci = 0; ci < 4; ++ci)
        *(float4*)&up[(size_t)(c0 + tc * 4 + ci) * 1024 + n0 + tn * 4] =
            make_float4(acc[ci][0], acc[ci][1], acc[ci][2], acc[ci][3]);
}

// ---------------------------------------------------------------------------
// K1b: U = sum_ks Upart[ks] + bp; SSp partial store. grid 128.  [proven]
__global__ void k_reduceU(const float* __restrict__ Upart, const float* __restrict__ bp,
                          float* __restrict__ U, float* __restrict__ SSp)
{
    __shared__ float red[256];
    const int blk = blockIdx.x, t = threadIdx.x;
    const int b = blk >> 5, cg = blk & 31;
    float ssq = 0.f;
#pragma unroll
    for (int i = 0; i < 4; ++i) {
        const int c = cg * 4 + i;
        const int f4 = b * 32768 + c * 256 + t;
        float4 s = ((const float4*)Upart)[f4];
#pragma unroll
        for (int ks = 1; ks < 4; ++ks) {
            const float4 p = ((const float4*)Upart)[ks * 131072 + f4];
            s.x += p.x; s.y += p.y; s.z += p.z; s.w += p.w;
        }
        const float bv = bp[c];
        s.x += bv; s.y += bv; s.z += bv; s.w += bv;
        ssq = fmaf(s.x, s.x, ssq); ssq = fmaf(s.y, s.y, ssq);
        ssq = fmaf(s.z, s.z, ssq); ssq = fmaf(s.w, s.w, ssq);
        ((float4*)U)[f4] = s;
    }
    red[t] = ssq;
    __syncthreads();
    for (int s = 128; s > 0; s >>= 1) {
        if (t < s) red[t] += red[t + s];
        __syncthreads();
    }
    if (t == 0) SSp[(b * 4 + (cg >> 3)) * 8 + (cg & 7)] = red[0];
}

// ---------------------------------------------------------------------------
// K4 "k_iter": ONE kernel per routing iteration = smatmul + (tbu | G).
// grid (16 mt, 4 us, 4 b) = 256 blocks, 256 thr.  [r8-proven math; r9 change:
// PERSISTENT full-q Ptf[128][68] staged once — removes the T-phase Pt restage
// (2 global re-read passes + 2 LDS write passes + 2 barriers). All accumulation
// orders unchanged -> bitwise-identical results vs r8.]
__global__ __launch_bounds__(256) void k_iter(
    const float* __restrict__ U, const float* __restrict__ SSp,
    float* __restrict__ Bgp2, const float* __restrict__ Wgr,
    float* __restrict__ Gp, const int first, const int last)
{
    __shared__ __align__(16) float Ptf[128 * 68];   // [q][m]  34816 B, persistent
    __shared__ __align__(16) float CtVs[64 * 160];  // Ct [qL][cpad] / later Vs [m][132]
    __shared__ float cls[512];
    __shared__ float bgs[512];
    __shared__ float bup[512];
    __shared__ float gacc[128];
    const int mt = blockIdx.x, us = blockIdx.y, b = blockIdx.z;
    const int t = threadIdx.x;
    const int tm = t >> 4;
    const int uu = t & 7, jh = (t >> 3) & 1;
    const int m0 = mt * 64;

    // ---- cls prologue
    if (first) {
        cls[t] = 0.0625f;            // softmax(0) == 1/16 exactly
        cls[t + 256] = 0.0625f;
    } else {
#pragma unroll
        for (int h = 0; h < 2; ++h) {
            const int p = t + h * 256;
            const float* bp2 = Bgp2 + (size_t)b * 32768 + p;
            float s = 0.f;
#pragma unroll 8
            for (int g = 0; g < 64; ++g) s += bp2[g * 512];
            bgs[p] = s * (1.f / 1024.f);
        }
        __syncthreads();
        if (t < 32) {
            float vals[16];
            float mx = -1e30f;
            for (int j = 0; j < 16; ++j) { vals[j] = bgs[t * 16 + j]; mx = fmaxf(mx, vals[j]); }
            float sum = 0.f;
            for (int j = 0; j < 16; ++j) { vals[j] = expf(vals[j] - mx); sum += vals[j]; }
            const float inv = 1.f / sum;
            for (int j = 0; j < 16; ++j) cls[t * 16 + j] = vals[j] * inv;
        }
    }
    if (last && t < 128) gacc[t] = 0.f;
    float ssum = 0.f;
#pragma unroll
    for (int i = 0; i < 8; ++i) ssum += SSp[(b * 4 + (mt >> 2)) * 8 + i];
    const float sc = sqrtf(ssum) / (1.f + ssum);
    float acc[4][8] = {};
    const float* Ub = U + (size_t)b * 131072 + (size_t)m0 * 128;

    // ---- stage persistent Ptf[q][m] for ALL q (one pass)
#pragma unroll
    for (int it = 0; it < 8; ++it) {
        const int x = t + it * 256;           // 0..2047
        const int m = x & 63, q4 = x >> 6;    // q4 0..31
        const float4 v = *(const float4*)&Ub[(size_t)m * 128 + q4 * 4];
        Ptf[(q4 * 4 + 0) * 68 + m] = v.x * sc;
        Ptf[(q4 * 4 + 1) * 68 + m] = v.y * sc;
        Ptf[(q4 * 4 + 2) * 68 + m] = v.z * sc;
        Ptf[(q4 * 4 + 3) * 68 + m] = v.w * sc;
    }
    __syncthreads();

    // ---- Phase 1: S  [r8 core; Pt reads from persistent Ptf]
    for (int kc = 0; kc < 2; ++kc) {
#pragma unroll
        for (int it = 0; it < 8; ++it) {
            const int x = t + it * 256;           // 0..2047
            const int c4 = (x & 31) * 4, qL = x >> 5;
            const int q = kc * 64 + qL;
            const int i = q & 31;
            const int j0 = c4 & 15;
            const float4 w = *(const float4*)&Wgr[(size_t)q * 512 + us * 128 + c4];
            const int cp = qL * 160 + c4 + ((c4 >> 4) << 2);
            CtVs[cp + 0] = cls[i * 16 + j0 + 0] * w.x;
            CtVs[cp + 1] = cls[i * 16 + j0 + 1] * w.y;
            CtVs[cp + 2] = cls[i * 16 + j0 + 2] * w.z;
            CtVs[cp + 3] = cls[i * 16 + j0 + 3] * w.w;
        }
        __syncthreads();
        const int cbase = uu * 20 + jh * 8;       // cpad of c = uu*16 + jh*8
#pragma unroll 4
        for (int qL = 0; qL < 64; ++qL) {
            const float4 p4 = *(const float4*)&Ptf[(kc * 64 + qL) * 68 + tm * 4];
            const float4 ca = *(const float4*)&CtVs[qL * 160 + cbase];
            const float4 cb = *(const float4*)&CtVs[qL * 160 + cbase + 4];
            const float pm[4] = {p4.x, p4.y, p4.z, p4.w};
            const float cj[8] = {ca.x, ca.y, ca.z, ca.w, cb.x, cb.y, cb.z, cb.w};
#pragma unroll
            for (int mm = 0; mm < 4; ++mm)
#pragma unroll
                for (int jj = 0; jj < 8; ++jj)
                    acc[mm][jj] = fmaf(pm[mm], cj[jj], acc[mm][jj]);
        }
        __syncthreads();
    }

    // ---- Phase 2: squash scale per (m,u) — full-j sum via jh-pair shfl
    float msc[4];
#pragma unroll
    for (int mm = 0; mm < 4; ++mm) {
        float msq = 0.f;
#pragma unroll
        for (int jj = 0; jj < 8; ++jj) msq = fmaf(acc[mm][jj], acc[mm][jj], msq);
        msq += __shfl_xor(msq, 8);
        msc[mm] = sqrtf(msq) / (1.f + msq);
    }

    if (last) {
        // ---- Phase 3': Gp partial store  [r8 code]
        float part[8];
#pragma unroll
        for (int jj = 0; jj < 8; ++jj) part[jj] = 0.f;
#pragma unroll
        for (int mm = 0; mm < 4; ++mm)
#pragma unroll
            for (int jj = 0; jj < 8; ++jj) part[jj] = fmaf(acc[mm][jj], msc[mm], part[jj]);
#pragma unroll
        for (int jj = 0; jj < 8; ++jj)
            atomicAdd(&gacc[(jh * 8 + jj) * 8 + uu], part[jj]);
        __syncthreads();
        if (t < 128) {
            const int j = t >> 3, u2 = t & 7;
            Gp[(size_t)(b * 16 + mt) * 512 + j * 32 + us * 8 + u2] =
                gacc[t] * (1.f / 1024.f);
        }
        return;
    }

    // ---- Phase 3: in-block tbu (Ptf persists — no restage)
    // V = acc*msc; stage Vs[m-local][jv'], jv' = j*8+uu = jh*64 + jj*8 + uu
    float* Vs = CtVs;                             // reuse Ct region (64*132 <= 64*160)
#pragma unroll
    for (int mm = 0; mm < 4; ++mm)
#pragma unroll
        for (int jj = 0; jj < 8; ++jj)
            Vs[(tm * 4 + mm) * 132 + jh * 64 + jj * 8 + uu] = acc[mm][jj] * msc[mm];
    __syncthreads();                              // Vs visible

    const int tq = t & 31, tjv = t >> 5;
    float acc2[4][16] = {};                       // [k][ji], ji = jl*8+uu_e
    // T: q = {tq, tq+32, 64+tq, 96+tq} -> i = tq, k = 0..3; all 4 k in one m-pass
#pragma unroll 2
    for (int m = 0; m < 64; ++m) {
        const float p00 = Ptf[tq * 68 + m];
        const float p01 = Ptf[(tq + 32) * 68 + m];
        const float p10 = Ptf[(64 + tq) * 68 + m];
        const float p11 = Ptf[(96 + tq) * 68 + m];
        const float4 v0 = *(const float4*)&Vs[m * 132 + tjv * 16];
        const float4 v1 = *(const float4*)&Vs[m * 132 + tjv * 16 + 4];
        const float4 v2 = *(const float4*)&Vs[m * 132 + tjv * 16 + 8];
        const float4 v3 = *(const float4*)&Vs[m * 132 + tjv * 16 + 12];
        const float vv[16] = {v0.x, v0.y, v0.z, v0.w, v1.x, v1.y, v1.z, v1.w,
                              v2.x, v2.y, v2.z, v2.w, v3.x, v3.y, v3.z, v3.w};
#pragma unroll
        for (int ji = 0; ji < 16; ++ji) {
            acc2[0][ji] = fmaf(p00, vv[ji], acc2[0][ji]);
            acc2[1][ji] = fmaf(p01, vv[ji], acc2[1][ji]);
            acc2[2][ji] = fmaf(p10, vv[ji], acc2[2][ji]);
            acc2[3][ji] = fmaf(p11, vv[ji], acc2[3][ji]);
        }
    }
    // epilogue: bup[i][j] = sum_{k,uu} acc2[k][jl*8+uu] * Wgr[(k*32+i)*512+u*16+j]
    // i = tq, j = tjv*2+jl  — single writer per (i,j), no atomics.
#pragma unroll
    for (int jl = 0; jl < 2; ++jl) {
        const int j = tjv * 2 + jl;
        float s = 0.f;
#pragma unroll
        for (int k = 0; k < 4; ++k) {
            const float* wr = Wgr + (size_t)(k * 32 + tq) * 512 + us * 128 + j;
#pragma unroll
            for (int ue = 0; ue < 8; ++ue)
                s = fmaf(wr[ue * 16], acc2[k][jl * 8 + ue], s);
        }
        bup[tq * 16 + j] = s;
    }
    __syncthreads();
    // Bgp2 partial per (b, mt, us): store (first) or += (later)
    {
        float* base = Bgp2 + (size_t)b * 32768 + (size_t)(mt * 4 + us) * 512;
#pragma unroll
        for (int h = 0; h < 2; ++h) {
            const int p = t + h * 256;
            if (first) base[p] = bup[p];
            else       base[p] += bup[p];
        }
    }
}

// ---------------------------------------------------------------------------
// K8a "uhat2": attention + aspect u_hat; G from Gp partials. grid (8, 4 b). [proven]
__global__ void k_uhat2(const float* __restrict__ Gp, const float* __restrict__ Wa,
                        const float* __restrict__ Ws, float* __restrict__ UH)
{
    const int b = blockIdx.y;
    const int t = threadIdx.x;
    __shared__ float g[512], cond[512], score[16], red[16];
    float g0 = 0.f, g1 = 0.f;
#pragma unroll 4
    for (int mt = 0; mt < 16; ++mt) {
        const float* gp = Gp + (size_t)(b * 16 + mt) * 512;
        g0 += gp[t];
        g1 += gp[t + 256];
    }
    g[t] = g0;
    g[t + 256] = g1;
    __syncthreads();
    if (t < 16) {
        float s = 0.f;
        for (int u = 0; u < 32; ++u) s = fmaf(g[t * 32 + u], Wa[u], s);
        red[t] = s;
    }
    __syncthreads();
    if (t == 0) {
        float mx = -1e30f;
        for (int j = 0; j < 16; ++j) mx = fmaxf(mx, red[j]);
        float sum = 0.f;
        for (int j = 0; j < 16; ++j) { score[j] = expf(red[j] - mx); sum += score[j]; }
        const float inv = 1.f / sum;
        for (int j = 0; j < 16; ++j) score[j] *= inv;
    }
    __syncthreads();
    cond[t] = g[t] * score[t >> 5];
    cond[t + 256] = g[t + 256] * score[(t + 256) >> 5];
    __syncthreads();
    const int e0 = blockIdx.x * 1024 + t * 4;
    const int i = e0 >> 9;
    const float* cp = cond + i * 32;
    const float* wp = Ws + (size_t)e0 * 32;
    float res[4];
#pragma unroll
    for (int jj = 0; jj < 4; ++jj) {
        float s = 0.f;
#pragma unroll
        for (int k8 = 0; k8 < 8; ++k8) {
            const float4 w = *(const float4*)(wp + jj * 32 + k8 * 4);
            s = fmaf(w.x, cp[k8 * 4 + 0], s);
            s = fmaf(w.y, cp[k8 * 4 + 1], s);
            s = fmaf(w.z, cp[k8 * 4 + 2], s);
            s = fmaf(w.w, cp[k8 * 4 + 3], s);
        }
        res[jj] = s;
    }
    ((float4*)UH)[(b * 8192 + e0) >> 2] = make_float4(res[0], res[1], res[2], res[3]);
}

// ---------------------------------------------------------------------------
// K8b "routeO": 3-iter aspect routing on LDS-resident UH + DIRECT output
// broadcast (k_out fused; writes are fire-and-forget, unlike r2's read-bound
// fusion). grid 4, 256 thr.
__global__ void k_routeO(const float* __restrict__ UH, float* __restrict__ out)
{
    const int b = blockIdx.x;
    const int t = threadIdx.x;
    __shared__ float uh[8192], ba[256], cc[256];
    __shared__ __align__(16) float sbuf[512];
    __shared__ float msc[32];
#pragma unroll
    for (int i = 0; i < 8; ++i)
        ((float4*)uh)[i * 256 + t] = ((const float4*)UH)[b * 2048 + i * 256 + t];
    ba[t] = 0.f;
    __syncthreads();
    for (int it = 0; it < 3; ++it) {
        if (t < 16) {
            float mx = -1e30f;
            for (int j = 0; j < 16; ++j) mx = fmaxf(mx, ba[t * 16 + j]);
            float sum = 0.f;
            for (int j = 0; j < 16; ++j) { cc[t * 16 + j] = expf(ba[t * 16 + j] - mx); sum += cc[t * 16 + j]; }
            const float inv = 1.f / sum;
            for (int j = 0; j < 16; ++j) cc[t * 16 + j] *= inv;
        }
        __syncthreads();
        for (int h = 0; h < 2; ++h) {
            const int e = h * 256 + t;
            const int j = e >> 5;
            float s = 0.f;
            for (int i = 0; i < 16; ++i) s = fmaf(cc[i * 16 + j], uh[i * 512 + e], s);
            sbuf[e] = s;
        }
        __syncthreads();
        if (t < 32) {
            float mg = 0.f;
            for (int j = 0; j < 16; ++j) { const float x = sbuf[j * 32 + t]; mg = fmaf(x, x, mg); }
            msc[t] = sqrtf(mg) / (1.f + mg);
        }
        __syncthreads();
        for (int h = 0; h < 2; ++h) {
            const int e = h * 256 + t;
            sbuf[e] *= msc[e & 31];
        }
        __syncthreads();
        if (it < 2) {
            const int i = t >> 4, j = t & 15;
            float s = 0.f;
            for (int u = 0; u < 32; ++u) s = fmaf(uh[i * 512 + j * 32 + u], sbuf[j * 32 + u], s);
            ba[t] += s;
            __syncthreads();
        }
    }
    // direct output broadcast: out[b][r][jv] = sbuf[jv] for all 512 rows.
    // thread owns column-chunk c4 = t&127, rows r = (t>>7), (t>>7)+2, ...
    const int c4 = t & 127;
    const float4 v = *(const float4*)&sbuf[c4 * 4];
    float* ob = out + (size_t)b * 262144;
#pragma unroll 8
    for (int r = t >> 7; r < 512; r += 2)
        *(float4*)&ob[(size_t)r * 512 + c4 * 4] = v;
}

// ---------------------------------------------------------------------------
extern "C" void kernel_launch(void* const* d_in, const int* in_sizes, int n_in,
                              void* d_out, int out_size, void* d_ws, size_t ws_size,
                              hipStream_t stream)
{
    const float* X   = (const float*)d_in[0];
    // d_in[1] = hidden — provably unused (softmax shift-invariance kills it)
    const float* Wp  = (const float*)d_in[2];
    const float* bp  = (const float*)d_in[3];
    const float* Wg  = (const float*)d_in[4];
    const float* Wa  = (const float*)d_in[5];
    const float* Wsp = (const float*)d_in[6];
    float* out = (float*)d_out;
    float* ws = (float*)d_ws;

    float* U    = ws + OFF_U;
    float* Up   = ws + OFF_UPART;
    float* SSp  = ws + OFF_SSP;
    float* Bgp2 = ws + OFF_BGP2;
    float* Gp   = ws + OFF_GP;
    float* UH   = ws + OFF_UH;
    float* Wgr  = ws + OFF_WGR;

    // primary GEMM partials (512 blocks) + z==16 one-time Wg reorder
    k_primary_part<<<dim3(2, 16, 17), 256, 0, stream>>>(X, Wp, Up, Wg, Wgr);
    k_reduceU<<<128, 256, 0, stream>>>(Up, bp, U, SSp);

    // routing: one kernel per iteration (smatmul + tbu fused; last does G)
    k_iter<<<dim3(16, 4, 4), 256, 0, stream>>>(U, SSp, Bgp2, Wgr, nullptr, 1, 0);
    k_iter<<<dim3(16, 4, 4), 256, 0, stream>>>(U, SSp, Bgp2, Wgr, nullptr, 0, 0);
    k_iter<<<dim3(16, 4, 4), 256, 0, stream>>>(U, SSp, Bgp2, Wgr, Gp, 0, 1);

    k_uhat2<<<dim3(8, 4), 256, 0, stream>>>(Gp, Wa, Wsp, UH);
    k_routeO<<<4, 256, 0, stream>>>(UH, out);
}